// Round 1
// baseline (218.215 us; speedup 1.0000x reference)
//
#include <hip/hip_runtime.h>
#include <cstdint>
#include <cstddef>

#define B_  16
#define S_  512
#define E_  768
#define NH_ 12
#define D_  64
#define M_  (B_*S_)   // 8192

typedef unsigned short u16;
typedef __attribute__((ext_vector_type(4))) float f32x4;
typedef __attribute__((ext_vector_type(8))) short bf16x8;

#define LOG2E 1.4426950408889634f

__device__ __forceinline__ u16 f2bf(float f){
  union { float fv; uint32_t u; } v; v.fv = f;
  uint32_t u = v.u;
  uint32_t r = u + 0x7fffu + ((u >> 16) & 1u);   // RNE
  return (u16)(r >> 16);
}

// ---------------- cast X fp32 -> bf16 ----------------
__global__ __launch_bounds__(256) void cast_x_kernel(const float* __restrict__ x,
                                                     u16* __restrict__ xb, int n4){
  int i = blockIdx.x * 256 + threadIdx.x;
  if (i < n4){
    float4 v = reinterpret_cast<const float4*>(x)[i];
    ushort4 o;
    o.x = f2bf(v.x); o.y = f2bf(v.y); o.z = f2bf(v.z); o.w = f2bf(v.w);
    reinterpret_cast<ushort4*>(xb)[i] = o;
  }
}

// ---------------- transpose W (E,H) fp32 -> Wt (H,E) bf16, 3 mats ----------------
__global__ __launch_bounds__(256) void transpose_w_kernel(const float* __restrict__ Wq,
                                                          const float* __restrict__ Wk,
                                                          const float* __restrict__ Wv,
                                                          u16* __restrict__ WtBase){
  __shared__ float t[32][33];
  const float* W = (blockIdx.z == 0) ? Wq : ((blockIdx.z == 1) ? Wk : Wv);
  u16* Wt = WtBase + (size_t)blockIdx.z * E_ * E_;
  int bx = blockIdx.x * 32, by = blockIdx.y * 32;
  int tx = threadIdx.x & 31, ty = threadIdx.x >> 5;
  #pragma unroll
  for (int i = 0; i < 32; i += 8)
    t[ty + i][tx] = W[(size_t)(by + ty + i) * E_ + bx + tx];
  __syncthreads();
  #pragma unroll
  for (int i = 0; i < 32; i += 8)
    Wt[(size_t)(bx + ty + i) * E_ + by + tx] = f2bf(t[tx][ty + i]);
}

// ---------------- fused QKV GEMM: C = Xb(8192x768) @ W(768x768) + bias ----------------
// Wt is pre-transposed [n][e] so both operands read 8 contiguous k (TN form).
// LDS tiles stored in fragment-chunk order: chunk c (16 rows x 32 k) = 1KB,
// lane L's fragment slice at chunk*1024 + L*16 bytes -> conflict-free ds_read_b128.
// z==2 (V) stores output transposed: Vt[bh][d][s] for attention B-operand loads.
__global__ __launch_bounds__(256) void qkv_gemm_kernel(
    const u16* __restrict__ Xb, const u16* __restrict__ WtBase,
    const float* __restrict__ bq, const float* __restrict__ bk, const float* __restrict__ bv,
    u16* __restrict__ Qb, u16* __restrict__ Kb, u16* __restrict__ VtB)
{
  __shared__ u16 lA[8 * 512];   // 8 chunks x 1KB
  __shared__ u16 lB[8 * 512];
  const int z = blockIdx.z;
  const u16* Wt = WtBase + (size_t)z * E_ * E_;
  const float* bias = (z == 0) ? bq : ((z == 1) ? bk : bv);
  const int m0 = blockIdx.x * 128;
  const int n0 = blockIdx.y * 128;
  const int tid = threadIdx.x;
  const int lane = tid & 63;
  const int wave = tid >> 6;
  const int wm = wave & 1, wn = wave >> 1;       // 2x2 waves of 64x64
  const int srow = lane >> 2, skq = lane & 3;    // staging: 4 lanes cover 64B of one row
  const int col0 = lane & 15, quad = lane >> 4;

  f32x4 acc[4][4];
  #pragma unroll
  for (int i = 0; i < 4; ++i)
    #pragma unroll
    for (int j = 0; j < 4; ++j)
      acc[i][j] = (f32x4){0.f, 0.f, 0.f, 0.f};

  #pragma unroll 1
  for (int k0 = 0; k0 < E_; k0 += 32){
    __syncthreads();
    #pragma unroll
    for (int cc = 0; cc < 2; ++cc){
      int c = wave * 2 + cc;
      uint4 va = *reinterpret_cast<const uint4*>(Xb + (size_t)(m0 + c*16 + srow) * E_ + k0 + skq*8);
      *reinterpret_cast<uint4*>(&lA[c*512 + (skq*16 + srow)*8]) = va;
      uint4 vb = *reinterpret_cast<const uint4*>(Wt + (size_t)(n0 + c*16 + srow) * E_ + k0 + skq*8);
      *reinterpret_cast<uint4*>(&lB[c*512 + (skq*16 + srow)*8]) = vb;
    }
    __syncthreads();
    bf16x8 af[4], bfr[4];
    #pragma unroll
    for (int mi = 0; mi < 4; ++mi)
      af[mi] = *reinterpret_cast<const bf16x8*>(&lA[(wm*4 + mi)*512 + lane*8]);
    #pragma unroll
    for (int ni = 0; ni < 4; ++ni)
      bfr[ni] = *reinterpret_cast<const bf16x8*>(&lB[(wn*4 + ni)*512 + lane*8]);
    #pragma unroll
    for (int mi = 0; mi < 4; ++mi)
      #pragma unroll
      for (int ni = 0; ni < 4; ++ni)
        acc[mi][ni] = __builtin_amdgcn_mfma_f32_16x16x32_bf16(af[mi], bfr[ni], acc[mi][ni], 0, 0, 0);
  }

  // epilogue: C/D layout col=lane&15, row=quad*4+r
  #pragma unroll
  for (int mi = 0; mi < 4; ++mi){
    #pragma unroll
    for (int ni = 0; ni < 4; ++ni){
      int n = n0 + wn*64 + ni*16 + col0;
      float bval = bias[n];
      int h = n >> 6, d = n & 63;
      #pragma unroll
      for (int r = 0; r < 4; ++r){
        int m = m0 + wm*64 + mi*16 + quad*4 + r;
        int b = m >> 9, s = m & 511;
        u16 obf = f2bf(acc[mi][ni][r] + bval);
        size_t bh = (size_t)b * NH_ + h;
        if (z == 0)      Qb[(bh * S_ + s) * D_ + d] = obf;
        else if (z == 1) Kb[(bh * S_ + s) * D_ + d] = obf;
        else             VtB[(bh * D_ + d) * S_ + s] = obf;  // transposed for attention
      }
    }
  }
}

// ---------------- flash attention ----------------
// grid: x = q-tile (8 of 64 rows), y = bh (192). 4 waves x 16 q-rows.
// K tile chunks: (ks in d, nt in key): lane slot key=L&15, d=quad*8+j
// Vt tile chunks: (ks2 in key, nd in d): lane slot d=L&15, key=quad*8+j
// P: per-wave 2 chunks (C-layout -> A-layout relayout through LDS).
__global__ __launch_bounds__(256) void attn_kernel(
    const u16* __restrict__ Qb, const u16* __restrict__ Kb, const u16* __restrict__ VtB,
    const float* __restrict__ mask, float* __restrict__ out)
{
  __shared__ u16 lK[8 * 512];
  __shared__ u16 lV[8 * 512];
  __shared__ u16 lP[4 * 1024];   // 2KB per wave
  __shared__ float biasS[S_];
  const int qt = blockIdx.x;
  const int bh = blockIdx.y;
  const int b = bh / NH_, h = bh % NH_;
  const int tid = threadIdx.x, lane = tid & 63, wave = tid >> 6;
  const int col0 = lane & 15, quad = lane >> 4;
  const int srow = lane >> 2, skq = lane & 3;

  for (int i = tid; i < S_; i += 256)
    biasS[i] = mask[b * S_ + i] * -1e9f;

  // Q fragments for this wave's 16 rows (A-operand layout)
  const int qrow = qt*64 + wave*16 + col0;
  bf16x8 qf[2];
  #pragma unroll
  for (int ks = 0; ks < 2; ++ks)
    qf[ks] = *reinterpret_cast<const bf16x8*>(Qb + ((size_t)bh * S_ + qrow) * D_ + ks*32 + quad*8);

  f32x4 o[4];
  #pragma unroll
  for (int i = 0; i < 4; ++i) o[i] = (f32x4){0.f, 0.f, 0.f, 0.f};
  float mold[4] = {-3.0e38f, -3.0e38f, -3.0e38f, -3.0e38f};
  float lold[4] = {0.f, 0.f, 0.f, 0.f};

  #pragma unroll 1
  for (int st = 0; st < 8; ++st){
    __syncthreads();
    #pragma unroll
    for (int gg = 0; gg < 4; ++gg){
      int g = wave * 4 + gg;           // 16 chunks: 0-7 K, 8-15 Vt
      if (g < 8){
        int ks = g >> 2, nt = g & 3;
        int key = st*64 + nt*16 + srow;
        int d = ks*32 + skq*8;
        uint4 v = *reinterpret_cast<const uint4*>(Kb + ((size_t)bh * S_ + key) * D_ + d);
        *reinterpret_cast<uint4*>(&lK[g*512 + (skq*16 + srow)*8]) = v;
      } else {
        int g2 = g - 8;
        int ks2 = g2 >> 2, nd = g2 & 3;
        int drow = nd*16 + srow;
        int key = st*64 + ks2*32 + skq*8;
        uint4 v = *reinterpret_cast<const uint4*>(VtB + ((size_t)bh * D_ + drow) * S_ + key);
        *reinterpret_cast<uint4*>(&lV[g2*512 + (skq*16 + srow)*8]) = v;
      }
    }
    __syncthreads();

    // scores: 16 q-rows x 64 keys
    f32x4 sc[4];
    #pragma unroll
    for (int nt = 0; nt < 4; ++nt) sc[nt] = (f32x4){0.f, 0.f, 0.f, 0.f};
    #pragma unroll
    for (int ks = 0; ks < 2; ++ks){
      #pragma unroll
      for (int nt = 0; nt < 4; ++nt){
        bf16x8 kf = *reinterpret_cast<const bf16x8*>(&lK[(ks*4 + nt)*512 + lane*8]);
        sc[nt] = __builtin_amdgcn_mfma_f32_16x16x32_bf16(qf[ks], kf, sc[nt], 0, 0, 0);
      }
    }
    float vv[4][4];
    #pragma unroll
    for (int nt = 0; nt < 4; ++nt){
      float bb = biasS[st*64 + nt*16 + col0];
      #pragma unroll
      for (int r = 0; r < 4; ++r) vv[nt][r] = sc[nt][r] * 0.125f + bb;
    }
    // online softmax: rows live in 16-lane groups; reduce via shfl_xor 1,2,4,8
    float mrow[4];
    #pragma unroll
    for (int r = 0; r < 4; ++r)
      mrow[r] = fmaxf(fmaxf(vv[0][r], vv[1][r]), fmaxf(vv[2][r], vv[3][r]));
    #pragma unroll
    for (int off = 1; off <= 8; off <<= 1)
      #pragma unroll
      for (int r = 0; r < 4; ++r)
        mrow[r] = fmaxf(mrow[r], __shfl_xor(mrow[r], off, 64));
    float mnew[4], alpha[4], rsum[4];
    #pragma unroll
    for (int r = 0; r < 4; ++r){
      mnew[r] = fmaxf(mold[r], mrow[r]);
      alpha[r] = exp2f((mold[r] - mnew[r]) * LOG2E);
      rsum[r] = 0.f;
    }
    // p = exp(v - mnew); write to per-wave P chunks in A-operand layout
    #pragma unroll
    for (int nt = 0; nt < 4; ++nt){
      int cc = nt*16 + col0;
      int chunkoff = wave*1024 + (nt >> 1)*512;
      int slotbase = ((cc & 31) >> 3) * 16;
      #pragma unroll
      for (int r = 0; r < 4; ++r){
        float p = exp2f((vv[nt][r] - mnew[r]) * LOG2E);
        rsum[r] += p;
        lP[chunkoff + (slotbase + quad*4 + r)*8 + (cc & 7)] = f2bf(p);
      }
    }
    #pragma unroll
    for (int off = 1; off <= 8; off <<= 1)
      #pragma unroll
      for (int r = 0; r < 4; ++r)
        rsum[r] += __shfl_xor(rsum[r], off, 64);
    #pragma unroll
    for (int r = 0; r < 4; ++r){
      lold[r] = alpha[r] * lold[r] + rsum[r];
      mold[r] = mnew[r];
    }
    #pragma unroll
    for (int nd = 0; nd < 4; ++nd)
      #pragma unroll
      for (int r = 0; r < 4; ++r)
        o[nd][r] *= alpha[r];
    // PV: P (A-layout from per-wave LDS) x V (B-layout chunks)
    bf16x8 pf[2];
    #pragma unroll
    for (int ks2 = 0; ks2 < 2; ++ks2)
      pf[ks2] = *reinterpret_cast<const bf16x8*>(&lP[wave*1024 + ks2*512 + lane*8]);
    #pragma unroll
    for (int ks2 = 0; ks2 < 2; ++ks2){
      #pragma unroll
      for (int nd = 0; nd < 4; ++nd){
        bf16x8 vf = *reinterpret_cast<const bf16x8*>(&lV[(ks2*4 + nd)*512 + lane*8]);
        o[nd] = __builtin_amdgcn_mfma_f32_16x16x32_bf16(pf[ks2], vf, o[nd], 0, 0, 0);
      }
    }
  }

  // epilogue: out (B,S,H*D) fp32
  #pragma unroll
  for (int r = 0; r < 4; ++r){
    int s = qt*64 + wave*16 + quad*4 + r;
    float inv = 1.0f / lold[r];
    #pragma unroll
    for (int nd = 0; nd < 4; ++nd){
      int d = nd*16 + col0;
      out[((size_t)b * S_ + s) * E_ + h*D_ + d] = o[nd][r] * inv;
    }
  }
}

extern "C" void kernel_launch(void* const* d_in, const int* in_sizes, int n_in,
                              void* d_out, int out_size, void* d_ws, size_t ws_size,
                              hipStream_t stream){
  const float* X    = (const float*)d_in[0];
  const float* mask = (const float*)d_in[1];
  const float* Wq   = (const float*)d_in[2];
  const float* bq   = (const float*)d_in[3];
  const float* Wk   = (const float*)d_in[4];
  const float* bk   = (const float*)d_in[5];
  const float* Wv   = (const float*)d_in[6];
  const float* bv   = (const float*)d_in[7];
  float* out = (float*)d_out;

  // workspace layout (bf16): Xb | Wt x3 | Qb | Kb | Vt  (~51.4 MB total)
  u16* Xb = (u16*)d_ws;
  u16* Wt = Xb + (size_t)M_ * E_;
  u16* Qb = Wt + (size_t)3 * E_ * E_;
  u16* Kb = Qb + (size_t)M_ * E_;
  u16* Vt = Kb + (size_t)M_ * E_;

  cast_x_kernel<<<(M_ * E_ / 4 + 255) / 256, 256, 0, stream>>>(X, Xb, M_ * E_ / 4);
  transpose_w_kernel<<<dim3(24, 24, 3), 256, 0, stream>>>(Wq, Wk, Wv, Wt);
  qkv_gemm_kernel<<<dim3(64, 6, 3), 256, 0, stream>>>(Xb, Wt, bq, bk, bv, Qb, Kb, Vt);
  attn_kernel<<<dim3(8, 192), 256, 0, stream>>>(Qb, Kb, Vt, mask, out);
}

// Round 2
// 214.377 us; speedup vs baseline: 1.0179x; 1.0179x over previous
//
#include <hip/hip_runtime.h>
#include <cstdint>
#include <cstddef>

#define B_  16
#define S_  512
#define E_  768
#define NH_ 12
#define D_  64
#define M_  (B_*S_)   // 8192

typedef unsigned short u16;
typedef __attribute__((ext_vector_type(4))) float f32x4;
typedef __attribute__((ext_vector_type(8))) short bf16x8;

#define LOG2E 1.4426950408889634f

__device__ __forceinline__ u16 f2bf(float f){
  union { float fv; uint32_t u; } v; v.fv = f;
  uint32_t u = v.u;
  uint32_t r = u + 0x7fffu + ((u >> 16) & 1u);   // RNE
  return (u16)(r >> 16);
}

// async global->LDS, 16B per lane; HW deposits lane L at ldsbase + L*16.
__device__ __forceinline__ void gload_lds16(const void* g, void* ldsbase){
  __builtin_amdgcn_global_load_lds(
      (const __attribute__((address_space(1))) unsigned int*)g,
      (__attribute__((address_space(3))) unsigned int*)ldsbase, 16, 0, 0);
}

// ---------------- cast X fp32 -> bf16 ----------------
__global__ __launch_bounds__(256) void cast_x_kernel(const float* __restrict__ x,
                                                     u16* __restrict__ xb, int n4){
  int i = blockIdx.x * 256 + threadIdx.x;
  if (i < n4){
    float4 v = reinterpret_cast<const float4*>(x)[i];
    ushort4 o;
    o.x = f2bf(v.x); o.y = f2bf(v.y); o.z = f2bf(v.z); o.w = f2bf(v.w);
    reinterpret_cast<ushort4*>(xb)[i] = o;
  }
}

// ---------------- transpose W (E,H) fp32 -> Wt (H,E) bf16, 3 mats ----------------
__global__ __launch_bounds__(256) void transpose_w_kernel(const float* __restrict__ Wq,
                                                          const float* __restrict__ Wk,
                                                          const float* __restrict__ Wv,
                                                          u16* __restrict__ WtBase){
  __shared__ float t[32][33];
  const float* W = (blockIdx.z == 0) ? Wq : ((blockIdx.z == 1) ? Wk : Wv);
  u16* Wt = WtBase + (size_t)blockIdx.z * E_ * E_;
  int bx = blockIdx.x * 32, by = blockIdx.y * 32;
  int tx = threadIdx.x & 31, ty = threadIdx.x >> 5;
  #pragma unroll
  for (int i = 0; i < 32; i += 8)
    t[ty + i][tx] = W[(size_t)(by + ty + i) * E_ + bx + tx];
  __syncthreads();
  #pragma unroll
  for (int i = 0; i < 32; i += 8)
    Wt[(size_t)(bx + ty + i) * E_ + by + tx] = f2bf(t[tx][ty + i]);
}

// ---------------- fused QKV GEMM: C = Xb(8192x768) @ W(768x768) + bias ----------------
// Staging via global_load_lds width=16: lane L deposits at chunk_base + L*16,
// and lane L reads global (row = L&15, k-octet = L>>4) -> LDS slot L IS the
// MFMA fragment slot (A[m=lane&15][k=quad*8+j]). No LDS staging writes, no
// bank conflicts, no VGPR round-trip.
__global__ __launch_bounds__(256) void qkv_gemm_kernel(
    const u16* __restrict__ Xb, const u16* __restrict__ WtBase,
    const float* __restrict__ bq, const float* __restrict__ bk, const float* __restrict__ bv,
    u16* __restrict__ Qb, u16* __restrict__ Kb, u16* __restrict__ VtB)
{
  __shared__ u16 lA[8 * 512];   // 8 chunks x 1KB  (chunk = 16 rows x 32 k)
  __shared__ u16 lB[8 * 512];
  const int z = blockIdx.z;
  const u16* Wt = WtBase + (size_t)z * E_ * E_;
  const float* bias = (z == 0) ? bq : ((z == 1) ? bk : bv);
  const int m0 = blockIdx.x * 128;
  const int n0 = blockIdx.y * 128;
  const int tid = threadIdx.x;
  const int lane = tid & 63;
  const int wave = tid >> 6;
  const int wm = wave & 1, wn = wave >> 1;       // 2x2 waves of 64x64
  const int ls = lane & 15;                      // staging row within chunk
  const int lk = lane >> 4;                      // staging k-octet
  const int col0 = lane & 15, quad = lane >> 4;

  f32x4 acc[4][4];
  #pragma unroll
  for (int i = 0; i < 4; ++i)
    #pragma unroll
    for (int j = 0; j < 4; ++j)
      acc[i][j] = (f32x4){0.f, 0.f, 0.f, 0.f};

  #pragma unroll 1
  for (int k0 = 0; k0 < E_; k0 += 32){
    __syncthreads();
    #pragma unroll
    for (int cc = 0; cc < 2; ++cc){
      int c = wave * 2 + cc;
      gload_lds16(Xb + (size_t)(m0 + c*16 + ls) * E_ + k0 + lk*8, &lA[c*512]);
      gload_lds16(Wt + (size_t)(n0 + c*16 + ls) * E_ + k0 + lk*8, &lB[c*512]);
    }
    __syncthreads();
    bf16x8 af[4], bfr[4];
    #pragma unroll
    for (int mi = 0; mi < 4; ++mi)
      af[mi] = *reinterpret_cast<const bf16x8*>(&lA[(wm*4 + mi)*512 + lane*8]);
    #pragma unroll
    for (int ni = 0; ni < 4; ++ni)
      bfr[ni] = *reinterpret_cast<const bf16x8*>(&lB[(wn*4 + ni)*512 + lane*8]);
    #pragma unroll
    for (int mi = 0; mi < 4; ++mi)
      #pragma unroll
      for (int ni = 0; ni < 4; ++ni)
        acc[mi][ni] = __builtin_amdgcn_mfma_f32_16x16x32_bf16(af[mi], bfr[ni], acc[mi][ni], 0, 0, 0);
  }

  // epilogue: C/D layout col=lane&15, row=quad*4+r
  #pragma unroll
  for (int mi = 0; mi < 4; ++mi){
    #pragma unroll
    for (int ni = 0; ni < 4; ++ni){
      int n = n0 + wn*64 + ni*16 + col0;
      float bval = bias[n];
      int h = n >> 6, d = n & 63;
      #pragma unroll
      for (int r = 0; r < 4; ++r){
        int m = m0 + wm*64 + mi*16 + quad*4 + r;
        int b = m >> 9, s = m & 511;
        u16 obf = f2bf(acc[mi][ni][r] + bval);
        size_t bh = (size_t)b * NH_ + h;
        if (z == 0)      Qb[(bh * S_ + s) * D_ + d] = obf;
        else if (z == 1) Kb[(bh * S_ + s) * D_ + d] = obf;
        else             VtB[(bh * D_ + d) * S_ + s] = obf;  // transposed for attention
      }
    }
  }
}

// ---------------- flash attention (S^T form) ----------------
// grid: x = q-tile (8 of 64 rows), y = bh (192). 4 waves x 16 q-rows.
// Scores computed TRANSPOSED: S^T = mfma(A=K, B=Q) -> C col = q, row = key.
// Payoff: the C-layout now aligns with the PV A-operand layout so P-writes
// pack into ds_write_b64, and softmax stats are one scalar per lane (q=lane&15)
// reduced with 2 shuffle stages instead of 4x4.
__global__ __launch_bounds__(256) void attn_kernel(
    const u16* __restrict__ Qb, const u16* __restrict__ Kb, const u16* __restrict__ VtB,
    const float* __restrict__ mask, float* __restrict__ out)
{
  __shared__ u16 lK[8 * 512];
  __shared__ u16 lV[8 * 512];
  __shared__ u16 lP[4 * 1024];   // 2KB per wave (16 q x 64 key, A-operand layout)
  __shared__ float biasS[S_];
  const int qt = blockIdx.x;
  const int bh = blockIdx.y;
  const int b = bh / NH_, h = bh % NH_;
  const int tid = threadIdx.x, lane = tid & 63, wave = tid >> 6;
  const int col0 = lane & 15, quad = lane >> 4;
  const int ls = lane & 15, lk = lane >> 4;      // async-staging row / k-octet

  for (int i = tid; i < S_; i += 256)
    biasS[i] = mask[b * S_ + i] * -1e9f;

  // Q fragments for this wave's 16 rows (B-operand now; same layout as A)
  const int qrow = qt*64 + wave*16 + col0;
  bf16x8 qf[2];
  #pragma unroll
  for (int ks = 0; ks < 2; ++ks)
    qf[ks] = *reinterpret_cast<const bf16x8*>(Qb + ((size_t)bh * S_ + qrow) * D_ + ks*32 + quad*8);

  f32x4 o[4];
  #pragma unroll
  for (int i = 0; i < 4; ++i) o[i] = (f32x4){0.f, 0.f, 0.f, 0.f};
  float mold = -3.0e38f;   // stats for q = lane&15 (replicated across quads)
  float lold = 0.f;

  #pragma unroll 1
  for (int st = 0; st < 8; ++st){
    __syncthreads();
    #pragma unroll
    for (int gg = 0; gg < 4; ++gg){
      int g = wave * 4 + gg;           // 16 chunks: 0-7 K, 8-15 Vt
      if (g < 8){
        int ks = g >> 2, nt = g & 3;
        gload_lds16(Kb + ((size_t)bh * S_ + st*64 + nt*16 + ls) * D_ + ks*32 + lk*8,
                    &lK[g*512]);
      } else {
        int g2 = g - 8;
        int ks2 = g2 >> 2, nd = g2 & 3;
        gload_lds16(VtB + ((size_t)bh * D_ + nd*16 + ls) * S_ + st*64 + ks2*32 + lk*8,
                    &lV[g2*512]);
      }
    }
    __syncthreads();

    // scores transposed: 64 keys (rows) x 16 q (cols)
    f32x4 sc[4];
    #pragma unroll
    for (int nt = 0; nt < 4; ++nt) sc[nt] = (f32x4){0.f, 0.f, 0.f, 0.f};
    #pragma unroll
    for (int ks = 0; ks < 2; ++ks){
      #pragma unroll
      for (int nt = 0; nt < 4; ++nt){
        bf16x8 kf = *reinterpret_cast<const bf16x8*>(&lK[(ks*4 + nt)*512 + lane*8]);
        sc[nt] = __builtin_amdgcn_mfma_f32_16x16x32_bf16(kf, qf[ks], sc[nt], 0, 0, 0);
      }
    }
    float vv[4][4];
    #pragma unroll
    for (int nt = 0; nt < 4; ++nt){
      // bias indexed by key = row = quad*4+r: one float4 LDS read per nt
      float4 bb = *reinterpret_cast<const float4*>(&biasS[st*64 + nt*16 + quad*4]);
      vv[nt][0] = sc[nt][0] * 0.125f + bb.x;
      vv[nt][1] = sc[nt][1] * 0.125f + bb.y;
      vv[nt][2] = sc[nt][2] * 0.125f + bb.z;
      vv[nt][3] = sc[nt][3] * 0.125f + bb.w;
    }
    // row (=q) max: local over 16 values, then across quads (xor 16, 32)
    float mrow = vv[0][0];
    #pragma unroll
    for (int nt = 0; nt < 4; ++nt)
      #pragma unroll
      for (int r = 0; r < 4; ++r)
        mrow = fmaxf(mrow, vv[nt][r]);
    mrow = fmaxf(mrow, __shfl_xor(mrow, 16, 64));
    mrow = fmaxf(mrow, __shfl_xor(mrow, 32, 64));
    float mnew = fmaxf(mold, mrow);
    float alpha = exp2f((mold - mnew) * LOG2E);
    float rsum = 0.f;
    // p = exp(v - mnew); pack 4 consecutive keys -> one b64 write per nt
    #pragma unroll
    for (int nt = 0; nt < 4; ++nt){
      ushort4 pw;
      float p0 = exp2f((vv[nt][0] - mnew) * LOG2E);
      float p1 = exp2f((vv[nt][1] - mnew) * LOG2E);
      float p2 = exp2f((vv[nt][2] - mnew) * LOG2E);
      float p3 = exp2f((vv[nt][3] - mnew) * LOG2E);
      rsum += (p0 + p1) + (p2 + p3);
      pw.x = f2bf(p0); pw.y = f2bf(p1); pw.z = f2bf(p2); pw.w = f2bf(p3);
      // A-layout addr: chunk=nt>>1, slot=((nt&1)*2+(quad>>1))*16+q, u16 pos=(quad&1)*4+r
      int addr = wave*1024 + (nt >> 1)*512
               + (((nt & 1)*2 + (quad >> 1))*16 + col0)*8 + (quad & 1)*4;
      *reinterpret_cast<ushort4*>(&lP[addr]) = pw;
    }
    rsum += __shfl_xor(rsum, 16, 64);
    rsum += __shfl_xor(rsum, 32, 64);
    lold = alpha * lold + rsum;
    mold = mnew;
    // rescale O: need alpha of q-row quad*4+r (row-space) from lane (lane&48)|(q)
    #pragma unroll
    for (int r = 0; r < 4; ++r){
      float ar = __shfl(alpha, (lane & 48) | (quad*4 + r), 64);
      #pragma unroll
      for (int nd = 0; nd < 4; ++nd)
        o[nd][r] *= ar;
    }
    // PV: P (A-layout, per-wave LDS) x V (B-layout chunks)
    bf16x8 pf[2];
    #pragma unroll
    for (int ks2 = 0; ks2 < 2; ++ks2)
      pf[ks2] = *reinterpret_cast<const bf16x8*>(&lP[wave*1024 + ks2*512 + lane*8]);
    #pragma unroll
    for (int ks2 = 0; ks2 < 2; ++ks2){
      #pragma unroll
      for (int nd = 0; nd < 4; ++nd){
        bf16x8 vf = *reinterpret_cast<const bf16x8*>(&lV[(ks2*4 + nd)*512 + lane*8]);
        o[nd] = __builtin_amdgcn_mfma_f32_16x16x32_bf16(pf[ks2], vf, o[nd], 0, 0, 0);
      }
    }
  }

  // epilogue: out (B,S,H*D) fp32; row s = q = quad*4+r, col d = nd*16+col0
  #pragma unroll
  for (int r = 0; r < 4; ++r){
    int s = qt*64 + wave*16 + quad*4 + r;
    float lr = __shfl(lold, (lane & 48) | (quad*4 + r), 64);
    float inv = 1.0f / lr;
    #pragma unroll
    for (int nd = 0; nd < 4; ++nd){
      int d = nd*16 + col0;
      out[((size_t)b * S_ + s) * E_ + h*D_ + d] = o[nd][r] * inv;
    }
  }
}

extern "C" void kernel_launch(void* const* d_in, const int* in_sizes, int n_in,
                              void* d_out, int out_size, void* d_ws, size_t ws_size,
                              hipStream_t stream){
  const float* X    = (const float*)d_in[0];
  const float* mask = (const float*)d_in[1];
  const float* Wq   = (const float*)d_in[2];
  const float* bq   = (const float*)d_in[3];
  const float* Wk   = (const float*)d_in[4];
  const float* bk   = (const float*)d_in[5];
  const float* Wv   = (const float*)d_in[6];
  const float* bv   = (const float*)d_in[7];
  float* out = (float*)d_out;

  // workspace layout (bf16): Xb | Wt x3 | Qb | Kb | Vt  (~51.4 MB total)
  u16* Xb = (u16*)d_ws;
  u16* Wt = Xb + (size_t)M_ * E_;
  u16* Qb = Wt + (size_t)3 * E_ * E_;
  u16* Kb = Qb + (size_t)M_ * E_;
  u16* Vt = Kb + (size_t)M_ * E_;

  cast_x_kernel<<<(M_ * E_ / 4 + 255) / 256, 256, 0, stream>>>(X, Xb, M_ * E_ / 4);
  transpose_w_kernel<<<dim3(24, 24, 3), 256, 0, stream>>>(Wq, Wk, Wv, Wt);
  qkv_gemm_kernel<<<dim3(64, 6, 3), 256, 0, stream>>>(Xb, Wt, bq, bk, bv, Qb, Kb, Vt);
  attn_kernel<<<dim3(8, 192), 256, 0, stream>>>(Qb, Kb, Vt, mask, out);
}